// Round 2
// baseline (191.867 us; speedup 1.0000x reference)
//
#include <hip/hip_runtime.h>

#define B_    32
#define CIN_  128
#define H_    64
#define W_    64
#define COUT_ 128
#define NK_   4
#define HID_  32
#define TEMP_ 34.0f

typedef short bf16x8 __attribute__((ext_vector_type(8)));
typedef float f32x16 __attribute__((ext_vector_type(16)));

__device__ __forceinline__ short f2bf(float f) {
    union { float f; unsigned u; } c; c.f = f;
    unsigned r = (c.u + 0x7FFFu + ((c.u >> 16) & 1u)) >> 16;
    return (short)r;
}

// =========== k_context: ctx[b][ci] = mean over HxW (one wave per (b,ci)) =====
__global__ __launch_bounds__(64) void k_context(const float* __restrict__ x,
                                                float* __restrict__ ctx) {
    const int bc = blockIdx.x;
    const float* p = x + (size_t)bc * (H_ * W_);
    const int lane = threadIdx.x;
    float s = 0.f;
    for (int i = lane * 4; i < H_ * W_; i += 64 * 4) {
        float4 v = *(const float4*)(p + i);
        s += v.x + v.y + v.z + v.w;
    }
    for (int off = 32; off > 0; off >>= 1) s += __shfl_down(s, off, 64);
    if (lane == 0) ctx[bc] = s * (1.0f / (H_ * W_));
}

// =========== k_aggw: fused attention + weight aggregation + agg bias =========
// Round-2 fix: the old per-thread (co,ci) loop read 4x9 floats at 36 B lane
// stride (9x VMEM transaction inflation). Now: flat coalesced float4 loads of
// the block's 2-co slice of all 4 kernels, aggregate, stage in LDS, then
// transpose-write bf16x8 to aggwt's [co][r][ci] layout.
__global__ __launch_bounds__(256) void k_aggw(const float* __restrict__ ctx,
        const float* __restrict__ fc1w, const float* __restrict__ fc2w,
        const float* __restrict__ fc2b, const float* __restrict__ bias,
        const float* __restrict__ weight, short* __restrict__ aggwt,
        float* __restrict__ aggb) {
    __shared__ float hidp[8][32];
    __shared__ float shid[32];
    __shared__ float satt[NK_];
    __shared__ float sbuf[2304];          // 2 co x 128 ci x 9 r, flat [coL][ci][r]
    const int t = threadIdx.x;
    const int blk = blockIdx.x;
    const int b = blk >> 6;               // 64 blocks per sample
    const int co0 = (blk & 63) * 2;
    // --- attention (tiny, redundant per block) ---
    {
        const int hh = t & 31, part = t >> 5;
        const float* c  = ctx + b * CIN_ + part * 16;
        const float* f1 = fc1w + hh * CIN_ + part * 16;
        float s = 0.f;
#pragma unroll
        for (int j = 0; j < 16; ++j) s += c[j] * f1[j];
        hidp[part][hh] = s;
    }
    __syncthreads();
    if (t < 32) {
        float s = 0.f;
#pragma unroll
        for (int p = 0; p < 8; ++p) s += hidp[p][t];
        shid[t] = fmaxf(s, 0.f);
    }
    __syncthreads();
    if (t == 0) {
        float lg[NK_]; float mx = -1e30f;
#pragma unroll
        for (int k = 0; k < NK_; ++k) {
            float s = fc2b[k];
            for (int hh = 0; hh < HID_; ++hh) s += shid[hh] * fc2w[k * HID_ + hh];
            lg[k] = s / TEMP_; mx = fmaxf(mx, lg[k]);
        }
        float den = 0.f;
#pragma unroll
        for (int k = 0; k < NK_; ++k) { lg[k] = expf(lg[k] - mx); den += lg[k]; }
        const float rd = 1.0f / den;
#pragma unroll
        for (int k = 0; k < NK_; ++k) satt[k] = lg[k] * rd;
    }
    __syncthreads();
    const float a0 = satt[0], a1 = satt[1], a2 = satt[2], a3 = satt[3];

    if ((t & 127) == 0) {
        const int co = co0 + (t >> 7);
        aggb[b * COUT_ + co] = a0 * bias[co] + a1 * bias[COUT_ + co]
                             + a2 * bias[2 * COUT_ + co] + a3 * bias[3 * COUT_ + co];
    }

    // --- coalesced aggregate: 576 float4 per k-stream ---
    const size_t kstride = (size_t)COUT_ * CIN_ * 9;
    const float* W0 = weight + (size_t)co0 * (CIN_ * 9);
#pragma unroll
    for (int jj = 0; jj < 3; ++jj) {
        const int i4 = jj * 256 + t;
        if (i4 < 576) {
            const float4 w0 = *(const float4*)(W0 + i4 * 4);
            const float4 w1 = *(const float4*)(W0 + kstride + i4 * 4);
            const float4 w2 = *(const float4*)(W0 + 2 * kstride + i4 * 4);
            const float4 w3 = *(const float4*)(W0 + 3 * kstride + i4 * 4);
            float4 r;
            r.x = a0 * w0.x + a1 * w1.x + a2 * w2.x + a3 * w3.x;
            r.y = a0 * w0.y + a1 * w1.y + a2 * w2.y + a3 * w3.y;
            r.z = a0 * w0.z + a1 * w1.z + a2 * w2.z + a3 * w3.z;
            r.w = a0 * w0.w + a1 * w1.w + a2 * w2.w + a3 * w3.w;
            *(float4*)(&sbuf[i4 * 4]) = r;
        }
    }
    __syncthreads();
    // --- transpose-write: group g = (coL, r, ci-octet), 288 groups ---
#pragma unroll
    for (int jj = 0; jj < 2; ++jj) {
        const int g = jj * 256 + t;
        if (g < 288) {
            const int coL = (g >= 144) ? 1 : 0;
            const int gg = g - coL * 144;
            const int r  = gg >> 4;
            const int oc = gg & 15;
            bf16x8 v;
#pragma unroll
            for (int e = 0; e < 8; ++e)
                v[e] = f2bf(sbuf[(coL * 128 + oc * 8 + e) * 9 + r]);
            short* dst = aggwt + ((size_t)(b * COUT_ + co0 + coL) * 9 + r) * CIN_ + oc * 8;
            *(bf16x8*)dst = v;
        }
    }
}

// =========== k_conv: 4-row x 32-col blocks, 3 waves/SIMD ===========
// Round-2 change: halve the per-wave w-tile (64 -> 32 cols) so acc drops from
// 128 to 64 AGPRs; with __launch_bounds__(256,3) we get 3 waves/SIMD (12/CU)
// to hide the ds_read->MFMA latency chain that capped MfmaUtil at 27%.
// LDS: 6 input rows x 34 slots x 8 chunks(16B) = 26112 B -> 3 blocks/CU.
// Swizzle identical: slot s holds w = iw*32 + s - 1; ci-octet g at chunk
// p = (g + s - 1) & 7; read for octet o at chunk (o + s - 1) & 7.
#define RBY2 4352           // bytes per LDS row (34 slots * 128 B)
#define RSH2 2176           // shorts per LDS row
__global__ __launch_bounds__(256, 3) void k_conv(const float* __restrict__ x,
        const short* __restrict__ aggwt, const float* __restrict__ aggb,
        float* __restrict__ out) {
    __shared__ short xt[6 * RSH2];
    const int tid = threadIdx.x;
    const int blk = blockIdx.x;
    const int b = blk & 31;                 // all 32 blocks of b on XCD b&7
    const int rest = blk >> 5;
    const int h0 = (rest >> 1) * 4;
    const int iw = rest & 1;
    const int lane = tid & 63;
    const int wv = tid >> 6;
    const int l31 = lane & 31;
    const int lane5 = lane >> 5;

    f32x16 acc[4];
#pragma unroll
    for (int t = 0; t < 4; ++t)
#pragma unroll
        for (int k = 0; k < 16; ++k) acc[t][k] = 0.f;

    const short* Ap = aggwt + (size_t)(b * COUT_ + wv * 32 + l31) * 9 * CIN_ + lane5 * 8;

    for (int half = 0; half < 2; ++half) {
        const int cib = half * 64;
        // stage 6 rows (ci-half): 48 wave-tasks (row 0..5, g 0..7), 12/wave.
        // lane l < 34 owns slot s=l (w = iw*32 - 1 + l); OOB lanes write zeros.
#pragma unroll
        for (int k = 0; k < 12; ++k) {
            const int task = k * 4 + wv;          // wave-uniform
            const int row = task >> 3;
            const int g = task & 7;
            const int in_h = h0 - 1 + row;
            if (lane < 34) {
                const int w = iw * 32 - 1 + lane;
                bf16x8 v = (bf16x8){0, 0, 0, 0, 0, 0, 0, 0};
                if (in_h >= 0 && in_h < H_ && w >= 0 && w < W_) {
                    const float* gp = x + (((size_t)b * CIN_ + cib + g * 8) * H_ + in_h) * W_ + w;
                    float f[8];
#pragma unroll
                    for (int j = 0; j < 8; ++j) f[j] = gp[j * (H_ * W_)];
#pragma unroll
                    for (int j = 0; j < 8; ++j) v[j] = f2bf(f[j]);
                }
                *(bf16x8*)(&xt[row * RSH2 + lane * 64 + ((g + lane - 1) & 7) * 8]) = v;
            }
        }
        __syncthreads();

#pragma unroll
        for (int kcl = 0; kcl < 4; ++kcl) {
            const int kc = half * 4 + kcl;
            bf16x8 av[9];
#pragma unroll
            for (int r = 0; r < 9; ++r)
                av[r] = *(const bf16x8*)(Ap + kc * 16 + r * CIN_);
#pragma unroll
            for (int ir = 0; ir < 6; ++ir) {
                bf16x8 bv[3];
#pragma unroll
                for (int kw = 0; kw < 3; ++kw) {
                    const int s = l31 + kw;
                    const int off = 16 * ((2 * kcl + lane5 + s - 1) & 7);
                    bv[kw] = *(const bf16x8*)((const char*)xt + ir * RBY2 + s * 128 + off);
                }
#pragma unroll
                for (int orr = 0; orr < 4; ++orr) {
                    if (orr <= ir && ir <= orr + 2) {
                        const int kh = ir - orr;
#pragma unroll
                        for (int kw = 0; kw < 3; ++kw)
                            acc[orr] = __builtin_amdgcn_mfma_f32_32x32x16_bf16(
                                av[kh * 3 + kw], bv[kw], acc[orr], 0, 0, 0);
                    }
                }
            }
        }
        if (half == 0) __syncthreads();     // drain readers before restaging
    }

    const float* ab = aggb + b * COUT_;
#pragma unroll
    for (int orr = 0; orr < 4; ++orr) {
        const int hh = h0 + orr;
        const int w = iw * 32 + l31;
        float* op = out + ((size_t)b * COUT_ * H_ + hh) * W_ + w;
        const f32x16 a = acc[orr];
#pragma unroll
        for (int reg = 0; reg < 16; ++reg) {
            const int co = wv * 32 + (reg & 3) + 8 * (reg >> 2) + 4 * lane5;
            op[(size_t)co * (H_ * W_)] = a[reg] + ab[co];
        }
    }
}

extern "C" void kernel_launch(void* const* d_in, const int* in_sizes, int n_in,
                              void* d_out, int out_size, void* d_ws, size_t ws_size,
                              hipStream_t stream) {
    const float* x    = (const float*)d_in[0];
    const float* fc1w = (const float*)d_in[1];
    const float* fc2w = (const float*)d_in[2];
    const float* fc2b = (const float*)d_in[3];
    const float* wgt  = (const float*)d_in[4];
    const float* bias = (const float*)d_in[5];
    float* out = (float*)d_out;

    char* ws = (char*)d_ws;
    float* ctx   = (float*)(ws + 0);            // 16 KB
    float* aggb  = (float*)(ws + 16384);        // 16 KB
    short* aggwt = (short*)(ws + 65536);        // 9,437,184 B

    k_context<<<dim3(B_ * CIN_), dim3(64), 0, stream>>>(x, ctx);
    k_aggw<<<dim3(B_ * (COUT_ / 2)), dim3(256), 0, stream>>>(
        ctx, fc1w, fc2w, fc2b, bias, wgt, aggwt, aggb);
    k_conv<<<dim3(B_ * (H_ / 4) * 2), dim3(256), 0, stream>>>(x, aggwt, aggb, out);
}

// Round 3
// 169.259 us; speedup vs baseline: 1.1336x; 1.1336x over previous
//
#include <hip/hip_runtime.h>

#define B_    32
#define CIN_  128
#define H_    64
#define W_    64
#define COUT_ 128
#define NK_   4
#define HID_  32
#define TEMP_ 34.0f

typedef short bf16x8 __attribute__((ext_vector_type(8)));
typedef float f32x16 __attribute__((ext_vector_type(16)));

__device__ __forceinline__ short f2bf(float f) {
    union { float f; unsigned u; } c; c.f = f;
    unsigned r = (c.u + 0x7FFFu + ((c.u >> 16) & 1u)) >> 16;
    return (short)r;
}

// =========== k_context: ctx[b][ci] = mean over HxW (one wave per (b,ci)) =====
__global__ __launch_bounds__(64) void k_context(const float* __restrict__ x,
                                                float* __restrict__ ctx) {
    const int bc = blockIdx.x;
    const float* p = x + (size_t)bc * (H_ * W_);
    const int lane = threadIdx.x;
    float s = 0.f;
    for (int i = lane * 4; i < H_ * W_; i += 64 * 4) {
        float4 v = *(const float4*)(p + i);
        s += v.x + v.y + v.z + v.w;
    }
    for (int off = 32; off > 0; off >>= 1) s += __shfl_down(s, off, 64);
    if (lane == 0) ctx[bc] = s * (1.0f / (H_ * W_));
}

// =========== k_aggw: fused attention + weight aggregation + agg bias =========
// Coalesced float4 reads of the block's 2-co slice of all 4 kernels, LDS
// transpose, then write aggwt in FRAGMENT-MAJOR layout so k_conv's per-wave
// A loads are contiguous 1KB:
//   aggwt[b][wg=co>>5][r][kc=ci>>4][co&31][(ci>>3)&1] : bf16x8
__global__ __launch_bounds__(256) void k_aggw(const float* __restrict__ ctx,
        const float* __restrict__ fc1w, const float* __restrict__ fc2w,
        const float* __restrict__ fc2b, const float* __restrict__ bias,
        const float* __restrict__ weight, short* __restrict__ aggwt,
        float* __restrict__ aggb) {
    __shared__ float hidp[8][32];
    __shared__ float shid[32];
    __shared__ float satt[NK_];
    __shared__ float sbuf[2304];          // 2 co x 128 ci x 9 r, flat [coL][ci][r]
    const int t = threadIdx.x;
    const int blk = blockIdx.x;
    const int b = blk >> 6;               // 64 blocks per sample
    const int co0 = (blk & 63) * 2;
    // --- attention (tiny, redundant per block) ---
    {
        const int hh = t & 31, part = t >> 5;
        const float* c  = ctx + b * CIN_ + part * 16;
        const float* f1 = fc1w + hh * CIN_ + part * 16;
        float s = 0.f;
#pragma unroll
        for (int j = 0; j < 16; ++j) s += c[j] * f1[j];
        hidp[part][hh] = s;
    }
    __syncthreads();
    if (t < 32) {
        float s = 0.f;
#pragma unroll
        for (int p = 0; p < 8; ++p) s += hidp[p][t];
        shid[t] = fmaxf(s, 0.f);
    }
    __syncthreads();
    if (t == 0) {
        float lg[NK_]; float mx = -1e30f;
#pragma unroll
        for (int k = 0; k < NK_; ++k) {
            float s = fc2b[k];
            for (int hh = 0; hh < HID_; ++hh) s += shid[hh] * fc2w[k * HID_ + hh];
            lg[k] = s / TEMP_; mx = fmaxf(mx, lg[k]);
        }
        float den = 0.f;
#pragma unroll
        for (int k = 0; k < NK_; ++k) { lg[k] = expf(lg[k] - mx); den += lg[k]; }
        const float rd = 1.0f / den;
#pragma unroll
        for (int k = 0; k < NK_; ++k) satt[k] = lg[k] * rd;
    }
    __syncthreads();
    const float a0 = satt[0], a1 = satt[1], a2 = satt[2], a3 = satt[3];

    if ((t & 127) == 0) {
        const int co = co0 + (t >> 7);
        aggb[b * COUT_ + co] = a0 * bias[co] + a1 * bias[COUT_ + co]
                             + a2 * bias[2 * COUT_ + co] + a3 * bias[3 * COUT_ + co];
    }

    // --- coalesced aggregate: 576 float4 per k-stream ---
    const size_t kstride = (size_t)COUT_ * CIN_ * 9;
    const float* W0 = weight + (size_t)co0 * (CIN_ * 9);
#pragma unroll
    for (int jj = 0; jj < 3; ++jj) {
        const int i4 = jj * 256 + t;
        if (i4 < 576) {
            const float4 w0 = *(const float4*)(W0 + i4 * 4);
            const float4 w1 = *(const float4*)(W0 + kstride + i4 * 4);
            const float4 w2 = *(const float4*)(W0 + 2 * kstride + i4 * 4);
            const float4 w3 = *(const float4*)(W0 + 3 * kstride + i4 * 4);
            float4 r;
            r.x = a0 * w0.x + a1 * w1.x + a2 * w2.x + a3 * w3.x;
            r.y = a0 * w0.y + a1 * w1.y + a2 * w2.y + a3 * w3.y;
            r.z = a0 * w0.z + a1 * w1.z + a2 * w2.z + a3 * w3.z;
            r.w = a0 * w0.w + a1 * w1.w + a2 * w2.w + a3 * w3.w;
            *(float4*)(&sbuf[i4 * 4]) = r;
        }
    }
    __syncthreads();
    // --- transpose-write to fragment-major: group g = (coL, r, ci-octet) ---
#pragma unroll
    for (int jj = 0; jj < 2; ++jj) {
        const int g = jj * 256 + t;
        if (g < 288) {
            const int coL = (g >= 144) ? 1 : 0;
            const int gg = g - coL * 144;
            const int r  = gg >> 4;
            const int oc = gg & 15;
            const int co = co0 + coL;
            bf16x8 v;
#pragma unroll
            for (int e = 0; e < 8; ++e)
                v[e] = f2bf(sbuf[(coL * 128 + oc * 8 + e) * 9 + r]);
            short* dst = aggwt
                + ((size_t)(((b * 4 + (co >> 5)) * 9 + r) * 8 + (oc >> 1)) * 512)
                + ((co & 31) * 2 + (oc & 1)) * 8;
            *(bf16x8*)dst = v;
        }
    }
}

// =========== k_conv: round-1 geometry (4 rows x 64 cols) + coalesced A ======
// Block = (b, 4 h-rows). LDS: 6 input rows x 66 slots x 8 chunks(16B) = 50688 B.
// Swizzle: data (w, ci8') at chunk p = (ci8' + w) & 7 of slot w+1.
// A loads now fragment-major: per (r,kc) one contiguous 1KB wave read.
#define RBY 8448            // bytes per LDS row (66 slots * 128 B)
#define RSH 4224            // shorts per LDS row
__global__ __launch_bounds__(256, 2) void k_conv(const float* __restrict__ x,
        const short* __restrict__ aggwt, const float* __restrict__ aggb,
        float* __restrict__ out) {
    __shared__ short xt[6 * RSH];
    const int tid = threadIdx.x;
    const int blk = blockIdx.x;
    const int b = blk & 31;                 // all 16 blocks of b on XCD b&7
    const int h0 = (blk >> 5) * 4;
    const int lane = tid & 63;
    const int wv = tid >> 6;
    const int l31 = lane & 31;
    const int lane5 = lane >> 5;

    // zero halo slots (slot 0 and slot 65 of each of 6 rows) - written once
    if (tid < 96) {
        const int row = tid >> 4;
        const int q = tid & 15;
        const int cl = (q < 8) ? q : (512 + q);
        *(int4*)(&xt[row * RSH + cl * 8]) = make_int4(0, 0, 0, 0);
    }

    f32x16 acc[8];
#pragma unroll
    for (int t = 0; t < 8; ++t)
#pragma unroll
        for (int k = 0; k < 16; ++k) acc[t][k] = 0.f;

    // fragment-major A: wave wv reads [b][wv][r][kc][l31][lane5] contiguous
    const short* Ap = aggwt + (size_t)(b * 4 + wv) * (9 * 8 * 512)
                            + (size_t)(l31 * 2 + lane5) * 8;

    for (int half = 0; half < 2; ++half) {
        const int cib = half * 64;
        // stage 6 rows (ci-half): 48 wave-tasks (row 0..5, g 0..7), 12/wave
#pragma unroll
        for (int k = 0; k < 12; ++k) {
            const int task = k * 4 + wv;          // wave-uniform
            const int row = task >> 3;
            const int g = task & 7;
            const int in_h = h0 - 1 + row;
            bf16x8 v = (bf16x8){0, 0, 0, 0, 0, 0, 0, 0};
            if (in_h >= 0 && in_h < H_) {
                const float* gp = x + (((size_t)b * CIN_ + cib + g * 8) * H_ + in_h) * W_ + lane;
                float f[8];
#pragma unroll
                for (int j = 0; j < 8; ++j) f[j] = gp[j * (H_ * W_)];
#pragma unroll
                for (int j = 0; j < 8; ++j) v[j] = f2bf(f[j]);
            }
            *(bf16x8*)(&xt[row * RSH + ((lane + 1) * 8 + ((g + lane) & 7)) * 8]) = v;
        }
        __syncthreads();

#pragma unroll
        for (int kcl = 0; kcl < 4; ++kcl) {
            const int kc = half * 4 + kcl;
            bf16x8 av[9];
#pragma unroll
            for (int r = 0; r < 9; ++r)
                av[r] = *(const bf16x8*)(Ap + ((size_t)(r * 8 + kc)) * 512);
#pragma unroll
            for (int ir = 0; ir < 6; ++ir) {
                bf16x8 bv[2][3];
#pragma unroll
                for (int i = 0; i < 2; ++i)
#pragma unroll
                    for (int kw = 0; kw < 3; ++kw) {
                        const int s = i * 32 + l31 + kw;
                        const int off = 16 * ((2 * kcl + lane5 + s - 1) & 7);
                        bv[i][kw] = *(const bf16x8*)((const char*)xt + ir * RBY + s * 128 + off);
                    }
#pragma unroll
                for (int orr = 0; orr < 4; ++orr) {
                    if (orr <= ir && ir <= orr + 2) {
                        const int kh = ir - orr;
#pragma unroll
                        for (int i = 0; i < 2; ++i)
#pragma unroll
                            for (int kw = 0; kw < 3; ++kw)
                                acc[orr * 2 + i] = __builtin_amdgcn_mfma_f32_32x32x16_bf16(
                                    av[kh * 3 + kw], bv[i][kw], acc[orr * 2 + i], 0, 0, 0);
                    }
                }
            }
        }
        if (half == 0) __syncthreads();     // drain readers before restaging
    }

    const float* ab = aggb + b * COUT_;
#pragma unroll
    for (int orr = 0; orr < 4; ++orr) {
#pragma unroll
        for (int i = 0; i < 2; ++i) {
            const int hh = h0 + orr;
            const int w = i * 32 + l31;
            float* op = out + ((size_t)b * COUT_ * H_ + hh) * W_ + w;
            const f32x16 a = acc[orr * 2 + i];
#pragma unroll
            for (int reg = 0; reg < 16; ++reg) {
                const int co = wv * 32 + (reg & 3) + 8 * (reg >> 2) + 4 * lane5;
                op[(size_t)co * (H_ * W_)] = a[reg] + ab[co];
            }
        }
    }
}

extern "C" void kernel_launch(void* const* d_in, const int* in_sizes, int n_in,
                              void* d_out, int out_size, void* d_ws, size_t ws_size,
                              hipStream_t stream) {
    const float* x    = (const float*)d_in[0];
    const float* fc1w = (const float*)d_in[1];
    const float* fc2w = (const float*)d_in[2];
    const float* fc2b = (const float*)d_in[3];
    const float* wgt  = (const float*)d_in[4];
    const float* bias = (const float*)d_in[5];
    float* out = (float*)d_out;

    char* ws = (char*)d_ws;
    float* ctx   = (float*)(ws + 0);            // 16 KB
    float* aggb  = (float*)(ws + 16384);        // 16 KB
    short* aggwt = (short*)(ws + 65536);        // 9,437,184 B

    k_context<<<dim3(B_ * CIN_), dim3(64), 0, stream>>>(x, ctx);
    k_aggw<<<dim3(B_ * (COUT_ / 2)), dim3(256), 0, stream>>>(
        ctx, fc1w, fc2w, fc2b, bias, wgt, aggwt, aggb);
    k_conv<<<dim3(B_ * (H_ / 4)), dim3(256), 0, stream>>>(x, aggwt, aggb, out);
}

// Round 5
// 165.366 us; speedup vs baseline: 1.1603x; 1.0235x over previous
//
#include <hip/hip_runtime.h>

#define B_    32
#define CIN_  128
#define H_    64
#define W_    64
#define COUT_ 128
#define NK_   4
#define HID_  32
#define TEMP_ 34.0f

typedef short bf16x8 __attribute__((ext_vector_type(8)));
typedef float f32x16 __attribute__((ext_vector_type(16)));

__device__ __forceinline__ short f2bf(float f) {
    union { float f; unsigned u; } c; c.f = f;
    unsigned r = (c.u + 0x7FFFu + ((c.u >> 16) & 1u)) >> 16;
    return (short)r;
}

// =========== k_context: ctx[b][ci] = mean over HxW (one wave per (b,ci)) =====
__global__ __launch_bounds__(64) void k_context(const float* __restrict__ x,
                                                float* __restrict__ ctx) {
    const int bc = blockIdx.x;
    const float* p = x + (size_t)bc * (H_ * W_);
    const int lane = threadIdx.x;
    float s = 0.f;
    for (int i = lane * 4; i < H_ * W_; i += 64 * 4) {
        float4 v = *(const float4*)(p + i);
        s += v.x + v.y + v.z + v.w;
    }
    for (int off = 32; off > 0; off >>= 1) s += __shfl_down(s, off, 64);
    if (lane == 0) ctx[bc] = s * (1.0f / (H_ * W_));
}

// =========== k_aggw: fused attention + weight aggregation + agg bias =========
// aggwt layout (fragment-major): [b][wg=co>>5][r][kc=ci>>4][co&31][(ci>>3)&1]
__global__ __launch_bounds__(256) void k_aggw(const float* __restrict__ ctx,
        const float* __restrict__ fc1w, const float* __restrict__ fc2w,
        const float* __restrict__ fc2b, const float* __restrict__ bias,
        const float* __restrict__ weight, short* __restrict__ aggwt,
        float* __restrict__ aggb) {
    __shared__ float hidp[8][32];
    __shared__ float shid[32];
    __shared__ float satt[NK_];
    __shared__ float sbuf[2304];          // 2 co x 128 ci x 9 r, flat [coL][ci][r]
    const int t = threadIdx.x;
    const int blk = blockIdx.x;
    const int b = blk >> 6;               // 64 blocks per sample
    const int co0 = (blk & 63) * 2;
    {
        const int hh = t & 31, part = t >> 5;
        const float* c  = ctx + b * CIN_ + part * 16;
        const float* f1 = fc1w + hh * CIN_ + part * 16;
        float s = 0.f;
#pragma unroll
        for (int j = 0; j < 16; ++j) s += c[j] * f1[j];
        hidp[part][hh] = s;
    }
    __syncthreads();
    if (t < 32) {
        float s = 0.f;
#pragma unroll
        for (int p = 0; p < 8; ++p) s += hidp[p][t];
        shid[t] = fmaxf(s, 0.f);
    }
    __syncthreads();
    if (t == 0) {
        float lg[NK_]; float mx = -1e30f;
#pragma unroll
        for (int k = 0; k < NK_; ++k) {
            float s = fc2b[k];
            for (int hh = 0; hh < HID_; ++hh) s += shid[hh] * fc2w[k * HID_ + hh];
            lg[k] = s / TEMP_; mx = fmaxf(mx, lg[k]);
        }
        float den = 0.f;
#pragma unroll
        for (int k = 0; k < NK_; ++k) { lg[k] = expf(lg[k] - mx); den += lg[k]; }
        const float rd = 1.0f / den;
#pragma unroll
        for (int k = 0; k < NK_; ++k) satt[k] = lg[k] * rd;
    }
    __syncthreads();
    const float a0 = satt[0], a1 = satt[1], a2 = satt[2], a3 = satt[3];

    if ((t & 127) == 0) {
        const int co = co0 + (t >> 7);
        aggb[b * COUT_ + co] = a0 * bias[co] + a1 * bias[COUT_ + co]
                             + a2 * bias[2 * COUT_ + co] + a3 * bias[3 * COUT_ + co];
    }

    const size_t kstride = (size_t)COUT_ * CIN_ * 9;
    const float* W0 = weight + (size_t)co0 * (CIN_ * 9);
#pragma unroll
    for (int jj = 0; jj < 3; ++jj) {
        const int i4 = jj * 256 + t;
        if (i4 < 576) {
            const float4 w0 = *(const float4*)(W0 + i4 * 4);
            const float4 w1 = *(const float4*)(W0 + kstride + i4 * 4);
            const float4 w2 = *(const float4*)(W0 + 2 * kstride + i4 * 4);
            const float4 w3 = *(const float4*)(W0 + 3 * kstride + i4 * 4);
            float4 r;
            r.x = a0 * w0.x + a1 * w1.x + a2 * w2.x + a3 * w3.x;
            r.y = a0 * w0.y + a1 * w1.y + a2 * w2.y + a3 * w3.y;
            r.z = a0 * w0.z + a1 * w1.z + a2 * w2.z + a3 * w3.z;
            r.w = a0 * w0.w + a1 * w1.w + a2 * w2.w + a3 * w3.w;
            *(float4*)(&sbuf[i4 * 4]) = r;
        }
    }
    __syncthreads();
#pragma unroll
    for (int jj = 0; jj < 2; ++jj) {
        const int g = jj * 256 + t;
        if (g < 288) {
            const int coL = (g >= 144) ? 1 : 0;
            const int gg = g - coL * 144;
            const int r  = gg >> 4;
            const int oc = gg & 15;
            const int co = co0 + coL;
            bf16x8 v;
#pragma unroll
            for (int e = 0; e < 8; ++e)
                v[e] = f2bf(sbuf[(coL * 128 + oc * 8 + e) * 9 + r]);
            short* dst = aggwt
                + ((size_t)(((b * 4 + (co >> 5)) * 9 + r) * 8 + (oc >> 1)) * 512)
                + ((co & 31) * 2 + (oc & 1)) * 8;
            *(bf16x8*)dst = v;
        }
    }
}

// =========== k_conv: kc-ring software pipeline (T3/T4/T5 style) ===========
// Block = (b, 4 h-rows). LDS: 6 rows x 66 slots x 8 chunks(16B) = 50688 B.
// Swizzle p = (octet + slot - 1) & 7 depends only on octet&7, so the buffer is
// a ring of 4 independent kc-slots (kc&3 = octet-pair). Pipeline per kc:
//   issue loads(kc+4) -> av(kc) + compute(kc) [setprio] -> barrier(kc<=4)
//   -> pack+ds_write(kc+4) into ring slot kc&3.
// Ring invariant: write kc+4 -> slot kc&3 only after barrier(kc) drains that
// slot's readers; write(kc) is separated from its readers (iter kc+4) by >=3
// barriers. Barriers stop after kc=4 (no further LDS writes).
#define RBY 8448            // bytes per LDS row (66 slots * 128 B)
#define RSH 4224            // shorts per LDS row
__global__ __launch_bounds__(256, 2) void k_conv(const float* __restrict__ x,
        const short* __restrict__ aggwt, const float* __restrict__ aggb,
        float* __restrict__ out) {
    __shared__ short xt[6 * RSH];
    const int tid = threadIdx.x;
    const int blk = blockIdx.x;
    const int b = blk & 31;                 // all 16 blocks of b on XCD b&7
    const int h0 = (blk >> 5) * 4;
    const int lane = tid & 63;
    const int wv = tid >> 6;
    const int l31 = lane & 31;
    const int lane5 = lane >> 5;

    // zero halo slots (slot 0 and slot 65 of each of 6 rows)
    if (tid < 96) {
        const int row = tid >> 4;
        const int q = tid & 15;
        const int cl = (q < 8) ? q : (512 + q);
        *(int4*)(&xt[row * RSH + cl * 8]) = make_int4(0, 0, 0, 0);
    }

    f32x16 acc[8];
#pragma unroll
    for (int t = 0; t < 8; ++t)
#pragma unroll
        for (int k = 0; k < 16; ++k) acc[t][k] = 0.f;

    // fragment-major A: wave wv reads [b][wv][r][kc][l31][lane5] contiguous
    const short* Ap = aggwt + (size_t)(b * 4 + wv) * (9 * 8 * 512)
                            + (size_t)(l31 * 2 + lane5) * 8;

    // ---- prologue: stage kc=0..3 (ci octets 0..7), 12 tasks/wave ----
#pragma unroll
    for (int k = 0; k < 12; ++k) {
        const int task = k * 4 + wv;          // wave-uniform
        const int row = task >> 3;
        const int g = task & 7;
        const int in_h = h0 - 1 + row;
        bf16x8 v = (bf16x8){0, 0, 0, 0, 0, 0, 0, 0};
        if (in_h >= 0 && in_h < H_) {
            const float* gp = x + (((size_t)b * CIN_ + g * 8) * H_ + in_h) * W_ + lane;
            float f[8];
#pragma unroll
            for (int j = 0; j < 8; ++j) f[j] = gp[j * (H_ * W_)];
#pragma unroll
            for (int j = 0; j < 8; ++j) v[j] = f2bf(f[j]);
        }
        *(bf16x8*)(&xt[row * RSH + ((lane + 1) * 8 + ((g + lane) & 7)) * 8]) = v;
    }
    __syncthreads();

    // ---- main ring loop over kc = 0..7 (16 ci each) ----
#pragma unroll
    for (int kc = 0; kc < 8; ++kc) {
        // (1) issue global loads for kc+4; sf indexed only by compile-time k
        float sf[3][8];
        if (kc < 4) {
#pragma unroll
            for (int k = 0; k < 3; ++k) {
                const int task = k * 4 + wv;      // 0..11, wave-uniform
                const int row = task >> 1;
                const int j = task & 1;
                const int in_h = h0 - 1 + row;
                if (in_h >= 0 && in_h < H_) {
                    const float* gp = x + (((size_t)b * CIN_ + 64 + (2 * kc + j) * 8) * H_
                                           + in_h) * W_ + lane;
#pragma unroll
                    for (int jj = 0; jj < 8; ++jj) sf[k][jj] = gp[jj * (H_ * W_)];
                }
            }
        }
        // (2) A fragments for this kc (contiguous 1KB wave reads)
        bf16x8 av[9];
#pragma unroll
        for (int r = 0; r < 9; ++r)
            av[r] = *(const bf16x8*)(Ap + ((size_t)(r * 8 + kc)) * 512);
        // (3) compute: 36 ds_read_b128 + 72 MFMA
        const int kcl = kc & 3;
        __builtin_amdgcn_s_setprio(1);
#pragma unroll
        for (int ir = 0; ir < 6; ++ir) {
            bf16x8 bv[2][3];
#pragma unroll
            for (int i = 0; i < 2; ++i)
#pragma unroll
                for (int kw = 0; kw < 3; ++kw) {
                    const int s = i * 32 + l31 + kw;
                    const int off = 16 * ((2 * kcl + lane5 + s - 1) & 7);
                    bv[i][kw] = *(const bf16x8*)((const char*)xt + ir * RBY + s * 128 + off);
                }
#pragma unroll
            for (int orr = 0; orr < 4; ++orr) {
                if (orr <= ir && ir <= orr + 2) {
                    const int kh = ir - orr;
#pragma unroll
                    for (int i = 0; i < 2; ++i)
#pragma unroll
                        for (int kw = 0; kw < 3; ++kw)
                            acc[orr * 2 + i] = __builtin_amdgcn_mfma_f32_32x32x16_bf16(
                                av[kh * 3 + kw], bv[i][kw], acc[orr * 2 + i], 0, 0, 0);
                }
            }
        }
        __builtin_amdgcn_s_setprio(0);
        // (4) barrier: protect ring slot kc&3 before overwrite; none for kc>4
        if (kc <= 4) __syncthreads();
        // (5) pack + write staged kc+4 into ring slot kc&3
        if (kc < 4) {
#pragma unroll
            for (int k = 0; k < 3; ++k) {
                const int task = k * 4 + wv;
                const int row = task >> 1;
                const int j = task & 1;
                const int in_h = h0 - 1 + row;
                const int g = 2 * kc + j;         // effective octet (global-8)
                bf16x8 v = (bf16x8){0, 0, 0, 0, 0, 0, 0, 0};
                if (in_h >= 0 && in_h < H_) {
#pragma unroll
                    for (int jj = 0; jj < 8; ++jj) v[jj] = f2bf(sf[k][jj]);
                }
                *(bf16x8*)(&xt[row * RSH + ((lane + 1) * 8 + ((g + lane) & 7)) * 8]) = v;
            }
        }
    }

    const float* ab = aggb + b * COUT_;
#pragma unroll
    for (int orr = 0; orr < 4; ++orr) {
#pragma unroll
        for (int i = 0; i < 2; ++i) {
            const int hh = h0 + orr;
            const int w = i * 32 + l31;
            float* op = out + ((size_t)b * COUT_ * H_ + hh) * W_ + w;
            const f32x16 a = acc[orr * 2 + i];
#pragma unroll
            for (int reg = 0; reg < 16; ++reg) {
                const int co = wv * 32 + (reg & 3) + 8 * (reg >> 2) + 4 * lane5;
                op[(size_t)co * (H_ * W_)] = a[reg] + ab[co];
            }
        }
    }
}

extern "C" void kernel_launch(void* const* d_in, const int* in_sizes, int n_in,
                              void* d_out, int out_size, void* d_ws, size_t ws_size,
                              hipStream_t stream) {
    const float* x    = (const float*)d_in[0];
    const float* fc1w = (const float*)d_in[1];
    const float* fc2w = (const float*)d_in[2];
    const float* fc2b = (const float*)d_in[3];
    const float* wgt  = (const float*)d_in[4];
    const float* bias = (const float*)d_in[5];
    float* out = (float*)d_out;

    char* ws = (char*)d_ws;
    float* ctx   = (float*)(ws + 0);            // 16 KB
    float* aggb  = (float*)(ws + 16384);        // 16 KB
    short* aggwt = (short*)(ws + 65536);        // 9,437,184 B

    k_context<<<dim3(B_ * CIN_), dim3(64), 0, stream>>>(x, ctx);
    k_aggw<<<dim3(B_ * (COUT_ / 2)), dim3(256), 0, stream>>>(
        ctx, fc1w, fc2w, fc2b, bias, wgt, aggwt, aggb);
    k_conv<<<dim3(B_ * (H_ / 4)), dim3(256), 0, stream>>>(x, aggwt, aggb, out);
}